// Round 14
// baseline (19.192 us; speedup 1.0000x reference)
//
#include <hip/hip_runtime.h>

// NeighborsConvolution: out[z,a,i] = sum_{b,x,j} [|r_b-r_a|<0.5] * (r_b-r_a)_x * W[x,i,j] * feat[z,b,j]
// B=8, N=1024, CIN=COUT=64.
//
// R14 vs R13 (W issue-bound; F~8us dominated by per-block prologue+barriers):
//  - 16 points per block (2 sets of 8), 512 blocks = 2/CU exactly. Prologue
//    (geo stage + W staging) amortized over 2x points; ramp halved.
//  - W staged in ONE pass (48KB, 6 float4/thread, rotate-swizzled) -> single
//    prologue barrier instead of 3 serial chunks x 2 barriers.
//  - 3 barriers total (prologue, post-tmp, post-red) vs 8.
//  - LDS 72KB: geo 12K | wstage 48K (red0/red1 alias inside after pickup) |
//    tmp0/tmp1 12K. __launch_bounds__(512,4).
//  - Per-point arithmetic bit-identical to R13 (scan subs, process order,
//    xj-split epilogue) -> absmax must stay exactly 0.015625.

#define BATCHSZ 8
#define NPTS 1024
#define CIN 64
#define COUT 64
#define NXJ (3 * CIN)      // 192
#define NG (NXJ / 4)       // 48 float4 groups
#define PPB 8              // waves per block (one point per wave per set)
#define PSETS 2            // point-sets per block
#define BS (PPB * 64)      // 512
#define GPW (NG / PPB)     // 6 W-groups per wave
#define NSTEP (NPTS / 64)  // 16 ballot steps

typedef float f32x2 __attribute__((ext_vector_type(2)));

// smem layout (floats):
//  [0,3072)        geo (12KB)                       live: whole kernel
//  [3072,15360)    wstage 48KB; after pickups, red0 @3072, red1 @7168 (16KB ea)
//  [15360,18432)   tmp0 (6KB) @15360, tmp1 @16896
#define SM_WS   3072
#define SM_TMP  15360
#define SM_TOTAL 18432

__global__ __launch_bounds__(BS, 4) void neigh_conv_kernel(
    const float* __restrict__ feat,  // [B,N,CIN]
    const float* __restrict__ geom,  // [B,N,3]
    const float* __restrict__ W,     // [3,COUT,CIN]
    float* __restrict__ out)         // [B,N,COUT]
{
    const int lane = threadIdx.x & 63;
    const int wv   = threadIdx.x >> 6;
    const int pbase = blockIdx.x * (PPB * PSETS);  // 16 consecutive points
    const int z     = pbase >> 10;                 // uniform (16 | 1024)
    const int abase = (pbase & (NPTS - 1)) + wv;   // set s point: abase + 8s

    __shared__ __align__(16) float smem[SM_TOTAL];

    // ---- prologue: stage geo (12KB) + ALL of W (48KB, swizzled), 1 barrier ----
    {
        const float4* src = (const float4*)(geom + (size_t)z * NPTS * 3);
        float4* dst = (float4*)smem;
        for (int k = threadIdx.x; k < NPTS * 3 / 4; k += BS)
            dst[k] = src[k];

        const float4* w4 = (const float4*)W;       // 3072 float4
        float4* ws = (float4*)(smem + SM_WS);
        #pragma unroll
        for (int kk = 0; kk < 6; ++kk) {           // 6 independent loads in flight
            const int k = threadIdx.x + kk * BS;
            // rotate swizzle: row i=k>>4, slot j4=k&15 -> (j4+i)&15
            const int idx = (k & ~15) | ((k + (k >> 4)) & 15);
            ws[idx] = w4[k];
        }
    }
    __syncthreads();   // B1: geo + wstage visible

    // ---- W fragment pickup (conflict-free rotated b128 reads) ----
    const int g0 = wv * GPW;
    float4 wr[GPW];
    {
        const float4* ws = (const float4*)(smem + SM_WS);
        #pragma unroll
        for (int q = 0; q < GPW; ++q) {
            const int g = g0 + q;
            const int x = g >> 4, c = g & 15;
            wr[q] = ws[x * 1024 + (lane << 4) + ((c + lane) & 15)];
        }
    }

    const float* geo = smem;
    const float* fz = feat + (size_t)z * NPTS * CIN;

    // ---- per-set: scan + process + tmp write (no barriers inside) ----
    #pragma unroll
    for (int s = 0; s < PSETS; ++s) {
        const int a = abase + s * PPB;
        const float gax = geo[a * 3 + 0];
        const float gay = geo[a * 3 + 1];
        const float gaz = geo[a * 3 + 2];

        unsigned long long masks[NSTEP];
        #pragma unroll
        for (int ss = 0; ss < NSTEP; ++ss) {
            const int b = ss * 64 + lane;
            float d2;
            {
                // Bit-exact vs numpy near boundary: no contraction, left-assoc.
                #pragma clang fp contract(off)
                const float dx = geo[b * 3 + 0] - gax;   // stride-3: conflict-free
                const float dy = geo[b * 3 + 1] - gay;
                const float dz = geo[b * 3 + 2] - gaz;
                d2 = dx * dx + dy * dy + dz * dz;
            }
            masks[ss] = __ballot(d2 < 0.25f);
        }

        // depth-2 pipelined mask-walk (bit-identical consume order)
        float acc0 = 0.f, acc1 = 0.f, acc2 = 0.f;
        int   b1 = -1, b2 = -1;
        float f1 = 0.f, f2 = 0.f;
        auto consume = [&](int bc, float fc) {
            const float dx = geo[bc * 3 + 0] - gax;  // uniform -> LDS broadcast
            const float dy = geo[bc * 3 + 1] - gay;
            const float dz = geo[bc * 3 + 2] - gaz;
            acc0 = fmaf(dx, fc, acc0);
            acc1 = fmaf(dy, fc, acc1);
            acc2 = fmaf(dz, fc, acc2);
        };
        #pragma unroll
        for (int ss = 0; ss < NSTEP; ++ss) {
            unsigned long long mm = masks[ss];
            while (mm) {                 // wave-uniform scalar walk
                const int src = __ffsll(mm) - 1;
                mm &= mm - 1ull;
                const int b = ss * 64 + src;
                const float f = fz[(size_t)b * CIN + lane];  // issue load now
                if (b2 >= 0) consume(b2, f2);
                b2 = b1; f2 = f1;
                b1 = b;  f1 = f;
            }
        }
        if (b2 >= 0) consume(b2, f2);
        if (b1 >= 0) consume(b1, f1);

        float* tmp = smem + SM_TMP + s * (PPB * NXJ) + wv * NXJ;
        tmp[0 * CIN + lane] = acc0;
        tmp[1 * CIN + lane] = acc1;
        tmp[2 * CIN + lane] = acc2;
    }
    __syncthreads();   // B2: all tmps visible; wstage pickups done -> red alias ok

    // ---- epilogues: wave wv owns groups [6wv,6wv+6), all 8 points, both sets ----
    #pragma unroll
    for (int s = 0; s < PSETS; ++s) {
        float* red = smem + SM_WS + s * (PPB * PPB * COUT);   // 16KB each
        #pragma unroll
        for (int pp = 0; pp < PPB; ++pp) {
            const float4* t4 = (const float4*)(smem + SM_TMP + s * (PPB * NXJ) + pp * NXJ);
            f32x2 facc = {0.f, 0.f};
            #pragma unroll
            for (int q = 0; q < GPW; ++q) {
                const float4 t = t4[g0 + q];          // uniform -> LDS broadcast
                f32x2 ta; ta.x = t.x; ta.y = t.y;
                f32x2 tb; tb.x = t.z; tb.y = t.w;
                f32x2 wa; wa.x = wr[q].x; wa.y = wr[q].y;
                f32x2 wb; wb.x = wr[q].z; wb.y = wr[q].w;
                facc = ta * wa + facc;                // v_pk_fma_f32
                facc = tb * wb + facc;
            }
            red[(wv * PPB + pp) * COUT + lane] = facc.x + facc.y;
        }
    }
    __syncthreads();   // B3

    // ---- reduce + store both sets ----
    #pragma unroll
    for (int s = 0; s < PSETS; ++s) {
        const float* red = smem + SM_WS + s * (PPB * PPB * COUT);
        float o = 0.f;
        #pragma unroll
        for (int w = 0; w < PPB; ++w)
            o += red[(w * PPB + wv) * COUT + lane];   // 2 lanes/bank: free
        out[(size_t)(pbase + s * PPB + wv) * COUT + lane] = o;
    }
}

extern "C" void kernel_launch(void* const* d_in, const int* in_sizes, int n_in,
                              void* d_out, int out_size, void* d_ws, size_t ws_size,
                              hipStream_t stream) {
    const float* feat = (const float*)d_in[0];  // [8,1024,64]
    const float* geom = (const float*)d_in[1];  // [8,1024,3]
    const float* W    = (const float*)d_in[2];  // [3,64,64]
    float* out        = (float*)d_out;          // [8,1024,64]

    const int nblocks = BATCHSZ * NPTS / (PPB * PSETS);   // 512 blocks x 512 thr
    neigh_conv_kernel<<<nblocks, BS, 0, stream>>>(feat, geom, W, out);
}

// Round 15
// 18.274 us; speedup vs baseline: 1.0502x; 1.0502x over previous
//
#include <hip/hip_runtime.h>

// NeighborsConvolution: out[z,a,i] = sum_{b,x,j} [|r_b-r_a|<0.5] * (r_b-r_a)_x * W[x,i,j] * feat[z,b,j]
// B=8, N=1024, CIN=COUT=64.
//
// R15 = R13 (best, 18.27us) + batch<->XCD affinity swizzle (T1, bijective).
// R9 counters: FETCH_SIZE ~10.4MB/dispatch = feat re-fetched & duplicated
// across all 8 XCD L2s (default round-robin bid%8->XCD scatters each batch's
// 128 blocks over all XCDs). Remap wid = ((bid&7)<<7)|(bid>>3) so batch z
// lands entirely on XCD z: each XCD fetches only its 256KB feat slice + 12KB
// geo + 48KB W (aggregate ~2.8MB vs 10.4MB), process-phase feat loads become
// local-L2 hits. 128 blocks/XCD = 4/CU, balanced; occupancy unchanged
// (34KB LDS, 4 blocks/CU = 32 waves/CU cap). Single-variable change vs R13.
// R14 lesson encoded: do NOT grow LDS past 4-blocks/CU configuration.

#define BATCHSZ 8
#define NPTS 1024
#define CIN 64
#define COUT 64
#define NXJ (3 * CIN)      // 192
#define NG (NXJ / 4)       // 48 float4 groups
#define PPB 8              // points (waves) per block
#define BS (PPB * 64)      // 512
#define GPW (NG / PPB)     // 6 W-groups per wave
#define NSTEP (NPTS / 64)  // 16 ballot steps

typedef float f32x2 __attribute__((ext_vector_type(2)));

// smem layout (floats):
//  [0,3072)     geo (12KB)                 live: stage -> end of process
//  [3072,7168)  wstage / red (16KB)        live: prologue staging, then epilogue red
//  [7168,8704)  tmp[8][192] (6KB)
#define SM_RED 3072
#define SM_TMP 7168
#define SM_TOTAL 8704

__global__ __launch_bounds__(BS, 8) void neigh_conv_kernel(
    const float* __restrict__ feat,  // [B,N,CIN]
    const float* __restrict__ geom,  // [B,N,3]
    const float* __restrict__ W,     // [3,COUT,CIN]
    float* __restrict__ out)         // [B,N,COUT]
{
    const int lane = threadIdx.x & 63;
    const int wv   = threadIdx.x >> 6;
    // batch<->XCD affinity: XCD = bid&7 (round-robin dispatch), batch = wid>>7.
    // Bijection on [0,1024): wid = (bid&7)*128 + bid/8.
    const int bid  = blockIdx.x;
    const int wid  = ((bid & 7) << 7) | (bid >> 3);
    const int p    = wid * PPB + wv;
    const int a    = p & (NPTS - 1);
    const int z    = p >> 10;        // == bid&7, uniform across block

    __shared__ __align__(16) float smem[SM_TOTAL];

    // ---- stage geometry (coalesced float4) ----
    {
        const float4* src = (const float4*)(geom + (size_t)z * NPTS * 3);
        float4* dst = (float4*)smem;
        for (int k = threadIdx.x; k < NPTS * 3 / 4; k += BS)
            dst[k] = src[k];
    }

    // ---- W fragment pickup via chunked LDS staging (16KB per x-chunk) ----
    // wr[q] = { W[x][lane][4c+e], e=0..3 }  with g = 6*wv+q, x = g>>4, c = g&15
    const int g0 = wv * GPW;
    float4 wr[GPW];
    {
        const float4* w4 = (const float4*)W;          // [3][1024] float4
        float4* ws = (float4*)(smem + SM_RED);        // 1024 float4
        for (int x = 0; x < 3; ++x) {
            __syncthreads();  // x=0: geo done; x>0: prev pickups done
            // stage chunk x, XOR-rotate swizzle: k=(i*16+j4) -> i*16+((j4+i)&15)
            #pragma unroll
            for (int kk = 0; kk < 2; ++kk) {
                const int k = threadIdx.x + kk * BS;
                const int idx = (k & ~15) | ((k + (k >> 4)) & 15);
                ws[idx] = w4[x * 1024 + k];           // coalesced global read
            }
            __syncthreads();
            #pragma unroll
            for (int q = 0; q < GPW; ++q) {
                const int g = g0 + q;
                if ((g >> 4) == x) {                  // wave-uniform
                    const int c = g & 15;
                    wr[q] = ws[(lane << 4) | ((c + lane) & 15)];  // conflict-free
                }
            }
        }
    }

    const float* geo = smem;
    const float gax = geo[a * 3 + 0];
    const float gay = geo[a * 3 + 1];
    const float gaz = geo[a * 3 + 2];
    const float* fz = feat + (size_t)z * NPTS * CIN;

    // ---- scan: 16 ballot steps; masks live wave-uniform (SGPR pairs) ----
    unsigned long long masks[NSTEP];
    #pragma unroll
    for (int ss = 0; ss < NSTEP; ++ss) {
        const int b = ss * 64 + lane;
        float d2;
        {
            // Bit-exact vs numpy near boundary: no contraction, left-assoc.
            #pragma clang fp contract(off)
            const float dx = geo[b * 3 + 0] - gax;   // stride-3: conflict-free
            const float dy = geo[b * 3 + 1] - gay;
            const float dz = geo[b * 3 + 2] - gaz;
            d2 = dx * dx + dy * dy + dz * dz;
        }
        masks[ss] = __ballot(d2 < 0.25f);
    }

    // ---- process: depth-2 pipelined mask-walk (2 feat loads in flight) ----
    float acc0 = 0.f, acc1 = 0.f, acc2 = 0.f;
    int   b1 = -1, b2 = -1;      // b1 = newest pending, b2 = oldest pending
    float f1 = 0.f, f2 = 0.f;

    auto consume = [&](int bc, float fc) {
        const float gbx = geo[bc * 3 + 0];   // uniform addr -> LDS broadcast
        const float gby = geo[bc * 3 + 1];
        const float gbz = geo[bc * 3 + 2];
        const float dx = gbx - gax;          // bit-identical to scan's diff
        const float dy = gby - gay;
        const float dz = gbz - gaz;
        acc0 = fmaf(dx, fc, acc0);
        acc1 = fmaf(dy, fc, acc1);
        acc2 = fmaf(dz, fc, acc2);
    };

    #pragma unroll
    for (int ss = 0; ss < NSTEP; ++ss) {
        unsigned long long mm = masks[ss];
        while (mm) {                     // wave-uniform scalar walk
            const int src = __ffsll(mm) - 1;
            mm &= mm - 1ull;
            const int b = ss * 64 + src;
            const float f = fz[(size_t)b * CIN + lane];  // issue load NOW
            if (b2 >= 0) consume(b2, f2);   // consume oldest (load landed)
            b2 = b1; f2 = f1;               // shift pipeline (reg moves only)
            b1 = b;  f1 = f;
        }
    }
    if (b2 >= 0) consume(b2, f2);        // drain (ascending order preserved)
    if (b1 >= 0) consume(b1, f1);

    float* tmp = smem + SM_TMP + wv * NXJ;
    tmp[0 * CIN + lane] = acc0;
    tmp[1 * CIN + lane] = acc1;
    tmp[2 * CIN + lane] = acc2;
    __syncthreads();   // pickups done, tmp visible; red free to write

    // ---- epilogue: wave wv owns W groups [6wv,6wv+6), all 8 points ----
    float* red = smem + SM_RED;   // red[wv*8+pp][i]
    #pragma unroll
    for (int pp = 0; pp < PPB; ++pp) {
        const float4* t4 = (const float4*)(smem + SM_TMP + pp * NXJ);
        f32x2 facc = {0.f, 0.f};
        #pragma unroll
        for (int q = 0; q < GPW; ++q) {
            const float4 t = t4[g0 + q];          // uniform -> LDS broadcast
            f32x2 ta; ta.x = t.x; ta.y = t.y;
            f32x2 tb; tb.x = t.z; tb.y = t.w;
            f32x2 wa; wa.x = wr[q].x; wa.y = wr[q].y;
            f32x2 wb; wb.x = wr[q].z; wb.y = wr[q].w;
            facc = ta * wa + facc;                // v_pk_fma_f32
            facc = tb * wb + facc;
        }
        red[(wv * PPB + pp) * COUT + lane] = facc.x + facc.y;
    }
    __syncthreads();

    float o = 0.f;
    #pragma unroll
    for (int w = 0; w < PPB; ++w)
        o += red[(w * PPB + wv) * COUT + lane];   // 2 lanes/bank: free

    out[(size_t)p * COUT + lane] = o;
}

extern "C" void kernel_launch(void* const* d_in, const int* in_sizes, int n_in,
                              void* d_out, int out_size, void* d_ws, size_t ws_size,
                              hipStream_t stream) {
    const float* feat = (const float*)d_in[0];  // [8,1024,64]
    const float* geom = (const float*)d_in[1];  // [8,1024,3]
    const float* W    = (const float*)d_in[2];  // [3,64,64]
    float* out        = (float*)d_out;          // [8,1024,64]

    const int nblocks = BATCHSZ * NPTS / PPB;   // 1024 blocks x 512 threads
    neigh_conv_kernel<<<nblocks, BS, 0, stream>>>(feat, geom, W, out);
}

// Round 16
// 18.076 us; speedup vs baseline: 1.0618x; 1.0110x over previous
//
#include <hip/hip_runtime.h>

// NeighborsConvolution: out[z,a,i] = sum_{b,x,j} [|r_b-r_a|<0.5] * (r_b-r_a)_x * W[x,i,j] * feat[z,b,j]
// B=8, N=1024, CIN=COUT=64.
//
// R16 = R14's prologue amortization WITH the occupancy fix.
// R14 failed because 512x512thr @72KB -> 16 waves/CU (halved TLP). Here:
// 512 blocks x 1024 threads (16 waves) @60KB -> 2 blocks/CU = 32 waves/CU (cap
// kept). 16 points/block: geo+W staged ONCE per 16 points; W staged in ONE
// pass (48KB region, 3 float4/thread, rotate swizzle) -> 1 staging barrier
// (vs 6 in R13). Barriers/point: 1.0 -> 0.31. LDS 60KB: geo region reused as
// tmp after a drain barrier; red0/red1 (two 8-wave halves) alias dead wstage.
// Scan/process/epilogue arithmetic bit-identical per point to R13.

#define BATCHSZ 8
#define NPTS 1024
#define CIN 64
#define COUT 64
#define NXJ (3 * CIN)      // 192
#define NG (NXJ / 4)       // 48 float4 groups
#define WPB 16             // waves (points) per block
#define BS (WPB * 64)      // 1024 threads
#define GPW (NG / 8)       // 6 W-groups per wave (xj-split within 8-wave half)
#define NSTEP (NPTS / 64)  // 16 ballot steps

typedef float f32x2 __attribute__((ext_vector_type(2)));

// smem layout (floats), 15360 floats = 60KB:
//  [0,3072)      geo (12KB)  -> after process-drain barrier: tmp[16][192]
//  [3072,15360)  wstage 48KB -> after pickups: red0 @3072, red1 @7168 (16KB ea)
#define SM_WS 3072
#define SM_TOTAL 15360

__global__ __launch_bounds__(BS, 8) void neigh_conv_kernel(
    const float* __restrict__ feat,  // [B,N,CIN]
    const float* __restrict__ geom,  // [B,N,3]
    const float* __restrict__ W,     // [3,COUT,CIN]
    float* __restrict__ out)         // [B,N,COUT]
{
    const int lane = threadIdx.x & 63;
    const int wv   = threadIdx.x >> 6;    // 0..15
    const int h    = wv >> 3;             // half 0/1
    const int hw   = wv & 7;              // wave within half
    const int p    = blockIdx.x * WPB + wv;
    const int a    = p & (NPTS - 1);
    const int z    = p >> 10;              // uniform across block (16 | 1024)

    __shared__ __align__(16) float smem[SM_TOTAL];

    // ---- prologue: stage geo (12KB) + ALL of W (48KB, swizzled); 1 barrier ----
    {
        const float4* gsrc = (const float4*)(geom + (size_t)z * NPTS * 3);
        float4* gdst = (float4*)smem;
        if (threadIdx.x < NPTS * 3 / 4)               // 768 of 1024 threads
            gdst[threadIdx.x] = gsrc[threadIdx.x];

        const float4* w4 = (const float4*)W;          // 3072 float4
        float4* ws = (float4*)(smem + SM_WS);
        #pragma unroll
        for (int kk = 0; kk < 3; ++kk) {              // 3 independent loads
            const int k = threadIdx.x + kk * BS;
            // rotate swizzle: row i=k>>4, slot j4=k&15 -> (j4+i)&15
            const int idx = (k & ~15) | ((k + (k >> 4)) & 15);
            ws[idx] = w4[k];
        }
    }
    __syncthreads();   // B1: geo + wstage visible

    // ---- W fragment pickup (rotated b128 reads; once per wave) ----
    const int g0 = hw * GPW;
    float4 wr[GPW];
    {
        const float4* ws = (const float4*)(smem + SM_WS);
        #pragma unroll
        for (int q = 0; q < GPW; ++q) {
            const int g = g0 + q;
            const int x = g >> 4, c = g & 15;
            wr[q] = ws[x * 1024 + (lane << 4) + ((c + lane) & 15)];
        }
    }

    const float* geo = smem;
    const float gax = geo[a * 3 + 0];
    const float gay = geo[a * 3 + 1];
    const float gaz = geo[a * 3 + 2];
    const float* fz = feat + (size_t)z * NPTS * CIN;

    // ---- scan: 16 ballot steps; masks live wave-uniform (SGPR pairs) ----
    unsigned long long masks[NSTEP];
    #pragma unroll
    for (int ss = 0; ss < NSTEP; ++ss) {
        const int b = ss * 64 + lane;
        float d2;
        {
            // Bit-exact vs numpy near boundary: no contraction, left-assoc.
            #pragma clang fp contract(off)
            const float dx = geo[b * 3 + 0] - gax;   // stride-3: conflict-free
            const float dy = geo[b * 3 + 1] - gay;
            const float dz = geo[b * 3 + 2] - gaz;
            d2 = dx * dx + dy * dy + dz * dz;
        }
        masks[ss] = __ballot(d2 < 0.25f);
    }

    // ---- process: depth-2 pipelined mask-walk (2 feat loads in flight) ----
    float acc0 = 0.f, acc1 = 0.f, acc2 = 0.f;
    int   b1 = -1, b2 = -1;
    float f1 = 0.f, f2 = 0.f;

    auto consume = [&](int bc, float fc) {
        const float gbx = geo[bc * 3 + 0];   // uniform addr -> LDS broadcast
        const float gby = geo[bc * 3 + 1];
        const float gbz = geo[bc * 3 + 2];
        const float dx = gbx - gax;          // bit-identical to scan's diff
        const float dy = gby - gay;
        const float dz = gbz - gaz;
        acc0 = fmaf(dx, fc, acc0);
        acc1 = fmaf(dy, fc, acc1);
        acc2 = fmaf(dz, fc, acc2);
    };

    #pragma unroll
    for (int ss = 0; ss < NSTEP; ++ss) {
        unsigned long long mm = masks[ss];
        while (mm) {                     // wave-uniform scalar walk
            const int src = __ffsll(mm) - 1;
            mm &= mm - 1ull;
            const int b = ss * 64 + src;
            const float f = fz[(size_t)b * CIN + lane];  // issue load NOW
            if (b2 >= 0) consume(b2, f2);
            b2 = b1; f2 = f1;            // shift pipeline (reg moves only)
            b1 = b;  f1 = f;
        }
    }
    if (b2 >= 0) consume(b2, f2);        // drain (ascending order preserved)
    if (b1 >= 0) consume(b1, f1);

    __syncthreads();   // B2a: ALL waves done reading geo -> region reusable

    float* tmp = smem + wv * NXJ;        // tmp[16][192] overlays geo
    tmp[0 * CIN + lane] = acc0;
    tmp[1 * CIN + lane] = acc1;
    tmp[2 * CIN + lane] = acc2;
    __syncthreads();   // B2b: tmps visible; wstage pickups long done -> red ok

    // ---- epilogue: per half, wave hw owns groups [6hw,6hw+6), 8 points ----
    float* red = smem + SM_WS + h * (8 * 8 * COUT);   // 16KB per half
    #pragma unroll
    for (int pp = 0; pp < 8; ++pp) {
        const float4* t4 = (const float4*)(smem + (h * 8 + pp) * NXJ);
        f32x2 facc = {0.f, 0.f};
        #pragma unroll
        for (int q = 0; q < GPW; ++q) {
            const float4 t = t4[g0 + q];          // uniform -> LDS broadcast
            f32x2 ta; ta.x = t.x; ta.y = t.y;
            f32x2 tb; tb.x = t.z; tb.y = t.w;
            f32x2 wa; wa.x = wr[q].x; wa.y = wr[q].y;
            f32x2 wb; wb.x = wr[q].z; wb.y = wr[q].w;
            facc = ta * wa + facc;                // v_pk_fma_f32
            facc = tb * wb + facc;
        }
        red[(hw * 8 + pp) * COUT + lane] = facc.x + facc.y;
    }
    __syncthreads();   // B3

    // ---- reduce within half + store ----
    float o = 0.f;
    #pragma unroll
    for (int w = 0; w < 8; ++w)
        o += red[(w * 8 + hw) * COUT + lane];     // 2 lanes/bank: free

    out[(size_t)p * COUT + lane] = o;
}

extern "C" void kernel_launch(void* const* d_in, const int* in_sizes, int n_in,
                              void* d_out, int out_size, void* d_ws, size_t ws_size,
                              hipStream_t stream) {
    const float* feat = (const float*)d_in[0];  // [8,1024,64]
    const float* geom = (const float*)d_in[1];  // [8,1024,3]
    const float* W    = (const float*)d_in[2];  // [3,64,64]
    float* out        = (float*)d_out;          // [8,1024,64]

    const int nblocks = BATCHSZ * NPTS / WPB;   // 512 blocks x 1024 threads
    neigh_conv_kernel<<<nblocks, BS, 0, stream>>>(feat, geom, W, out);
}